// Round 4
// baseline (445.735 us; speedup 1.0000x reference)
//
#include <hip/hip_runtime.h>
#include <hip/hip_bf16.h>
#include <math.h>

#define N_NODES 50000
#define N_EDGES 800000
#define C 64
#define EPS_F 1.000001f
#define TWO_N (2 * N_NODES)

// CSR is partitioned by edge-block cohort p = blockIdx & 7 (heuristic match to
// round-robin XCD dispatch) so all writes to a given rec[] cache line come from
// one XCD -> kills the 8x HBM write amplification seen in round 3 (104 MB for a
// 12.8 MB array). deg/off/cur are indexed [p][conv][node].
#define NPART 8
#define DEG_SZ (NPART * TWO_N)                       // 800000 bins
#define SCAN_TILE 1024
#define NB_SCAN ((DEG_SZ + SCAN_TILE - 1) / SCAN_TILE)  // 782 blocks
#define DEG_PAD (NB_SCAN * SCAN_TILE)                // padded to tile multiple

// ---------------------------------------------------------------------------
// Kernel A: per-node precompute. One wave per 4 node rows (amortize LDS reads).
//   xm_l = x @ w_l ; xm_u = x @ w_u ; xlin = (x @ w_lin) * EPS
//   s_src_* = xm_* @ a_*[:64] ; s_tgt_* = xm_* @ a_*[64:]
// ---------------------------------------------------------------------------
__global__ __launch_bounds__(256) void precompute_kernel(
    const float* __restrict__ x,
    const float* __restrict__ w_l, const float* __restrict__ a_l,
    const float* __restrict__ w_u, const float* __restrict__ a_u,
    const float* __restrict__ w_lin,
    float* __restrict__ xm_l, float* __restrict__ xm_u,
    float* __restrict__ s_src_l, float* __restrict__ s_tgt_l,
    float* __restrict__ s_src_u, float* __restrict__ s_tgt_u,
    float* __restrict__ xlin)
{
    __shared__ float lw_l[C * C];
    __shared__ float lw_u[C * C];
    __shared__ float lw_n[C * C];
    __shared__ float la_l[2 * C];
    __shared__ float la_u[2 * C];

    const int t = threadIdx.x;
    for (int idx = t; idx < C * C; idx += 256) {
        lw_l[idx] = w_l[idx];
        lw_u[idx] = w_u[idx];
        lw_n[idx] = w_lin[idx];
    }
    if (t < 2 * C) { la_l[t] = a_l[t]; la_u[t] = a_u[t]; }
    __syncthreads();

    const int wave = t >> 6;
    const int lane = t & 63;
    const int row0 = (blockIdx.x * 4 + wave) * 4;   // 4 rows per wave

    float xv[4];
#pragma unroll
    for (int r = 0; r < 4; ++r) {
        const int row = row0 + r;
        xv[r] = (row < N_NODES) ? x[row * C + lane] : 0.f;
    }

    float acc_l[4] = {0.f, 0.f, 0.f, 0.f};
    float acc_u[4] = {0.f, 0.f, 0.f, 0.f};
    float acc_n[4] = {0.f, 0.f, 0.f, 0.f};

#pragma unroll 16
    for (int k = 0; k < C; ++k) {
        const float wl = lw_l[k * C + lane];
        const float wu = lw_u[k * C + lane];
        const float wn = lw_n[k * C + lane];
#pragma unroll
        for (int r = 0; r < 4; ++r) {
            const float xk = __shfl(xv[r], k);
            acc_l[r] = fmaf(xk, wl, acc_l[r]);
            acc_u[r] = fmaf(xk, wu, acc_u[r]);
            acc_n[r] = fmaf(xk, wn, acc_n[r]);
        }
    }

#pragma unroll
    for (int r = 0; r < 4; ++r) {
        const int row = row0 + r;
        if (row >= N_NODES) break;
        xm_l[row * C + lane] = acc_l[r];
        xm_u[row * C + lane] = acc_u[r];
        xlin[row * C + lane] = acc_n[r] * EPS_F;

        float ssl = acc_l[r] * la_l[lane];
        float stl = acc_l[r] * la_l[C + lane];
        float ssu = acc_u[r] * la_u[lane];
        float stu = acc_u[r] * la_u[C + lane];
#pragma unroll
        for (int off = 32; off >= 1; off >>= 1) {
            ssl += __shfl_xor(ssl, off);
            stl += __shfl_xor(stl, off);
            ssu += __shfl_xor(ssu, off);
            stu += __shfl_xor(stu, off);
        }
        if (lane == 0) {
            s_src_l[row] = ssl;
            s_tgt_l[row] = stl;
            s_src_u[row] = ssu;
            s_tgt_u[row] = stu;
        }
    }
}

// ---------------------------------------------------------------------------
// Kernel B1: degree histogram into partitioned bins deg[p][cv][node].
// Edge->partition mapping (blockIdx & 7) MUST match fill_kernel's.
// ---------------------------------------------------------------------------
__global__ __launch_bounds__(256) void hist_kernel(
    const int* __restrict__ lidx, const int* __restrict__ uidx,
    int* __restrict__ deg)
{
    const int g = blockIdx.x * 256 + threadIdx.x;
    const int p = blockIdx.x & (NPART - 1);
    if (g >= 2 * N_EDGES) return;
    if (g < N_EDGES) atomicAdd(&deg[p * TWO_N + lidx[g]], 1);
    else             atomicAdd(&deg[p * TWO_N + N_NODES + uidx[g - N_EDGES]], 1);
}

// ---------------------------------------------------------------------------
// Kernel S1: per-tile sums (1024 elems / 256-thread block, int4 loads).
// deg is padded+zeroed to DEG_PAD so no bounds checks.
// ---------------------------------------------------------------------------
__global__ __launch_bounds__(256) void block_sum_kernel(
    const int* __restrict__ deg, int* __restrict__ bsum)
{
    const int t = threadIdx.x;
    const int4 d = ((const int4*)deg)[blockIdx.x * 256 + t];
    int v = d.x + d.y + d.z + d.w;
#pragma unroll
    for (int o = 32; o >= 1; o >>= 1) v += __shfl_xor(v, o);
    __shared__ int ws[4];
    if ((t & 63) == 0) ws[t >> 6] = v;
    __syncthreads();
    if (t == 0) bsum[blockIdx.x] = ws[0] + ws[1] + ws[2] + ws[3];
}

// ---------------------------------------------------------------------------
// Kernel S2: inclusive scan of NB_SCAN (<=1024) tile sums, one 1024 block.
// ---------------------------------------------------------------------------
__global__ __launch_bounds__(1024) void scan_bsum_kernel(int* __restrict__ bsum)
{
    __shared__ int s[1024];
    const int t = threadIdx.x;
    s[t] = (t < NB_SCAN) ? bsum[t] : 0;
    __syncthreads();
    for (int o = 1; o < 1024; o <<= 1) {
        const int y = (t >= o) ? s[t - o] : 0;
        __syncthreads();
        s[t] += y;
        __syncthreads();
    }
    if (t < NB_SCAN) bsum[t] = s[t];   // inclusive
}

// ---------------------------------------------------------------------------
// Kernel S3: apply — exclusive scan of deg into off[] / cur[].
// 4 elems/thread (int4) + wave shuffle scan + LDS wave combine + tile prefix.
// ---------------------------------------------------------------------------
__global__ __launch_bounds__(256) void scan_apply_kernel(
    const int* __restrict__ deg, const int* __restrict__ bscan,
    int* __restrict__ off, int* __restrict__ cur)
{
    const int b = blockIdx.x, t = threadIdx.x;
    const int lane = t & 63, wv = t >> 6;
    const int g4 = (b * 256 + t) * 4;

    const int4 d = ((const int4*)deg)[b * 256 + t];
    int e0 = 0, e1 = d.x, e2 = d.x + d.y, e3 = d.x + d.y + d.z;
    const int tot = e3 + d.w;

    int inc = tot;
#pragma unroll
    for (int o = 1; o < 64; o <<= 1) {
        const int y = __shfl_up(inc, o);
        if (lane >= o) inc += y;
    }
    __shared__ int wsum[4];
    if (lane == 63) wsum[wv] = inc;
    __syncthreads();
    int wpre = 0;
    for (int w = 0; w < wv; ++w) wpre += wsum[w];

    const int bpre = (b == 0) ? 0 : bscan[b - 1];
    const int base = bpre + wpre + (inc - tot);

    const int vals[4] = { base + e0, base + e1, base + e2, base + e3 };
#pragma unroll
    for (int k = 0; k < 4; ++k) {
        const int f = g4 + k;
        if (f < DEG_SZ) { off[f] = vals[k]; cur[f] = vals[k]; }
        else if (f == DEG_SZ) { off[f] = vals[k]; }
    }
}

// ---------------------------------------------------------------------------
// Kernel B3: CSR fill into partitioned rec[]. Per edge: alpha =
// elu(s_src[j]+s_tgt[i])*val; claim slot under (p, conv, target).
// ---------------------------------------------------------------------------
__global__ __launch_bounds__(256) void fill_kernel(
    const int* __restrict__ lidx, const float* __restrict__ lval,
    const float* __restrict__ ssl, const float* __restrict__ stl,
    const int* __restrict__ uidx, const float* __restrict__ uval,
    const float* __restrict__ ssu, const float* __restrict__ stu,
    int* __restrict__ cur, float2* __restrict__ rec)
{
    const int g = blockIdx.x * 256 + threadIdx.x;
    const int p = blockIdx.x & (NPART - 1);
    if (g >= 2 * N_EDGES) return;

    if (g < N_EDGES) {
        const int e = g;
        const int i = lidx[e];
        const int j = lidx[N_EDGES + e];
        float s = ssl[j] + stl[i];
        s = (s > 0.f) ? s : expm1f(s);
        const float a = s * lval[e];
        const int slot = atomicAdd(&cur[p * TWO_N + i], 1);
        rec[slot] = make_float2(__int_as_float(j), a);
    } else {
        const int e = g - N_EDGES;
        const int i = uidx[e];
        const int j = uidx[N_EDGES + e];
        float s = ssu[j] + stu[i];
        s = (s > 0.f) ? s : expm1f(s);
        const float a = s * uval[e];
        const int slot = atomicAdd(&cur[p * TWO_N + N_NODES + i], 1);
        rec[slot] = make_float2(__int_as_float(j), a);
    }
}

// ---------------------------------------------------------------------------
// Kernel D: gather + fuse. One wave per node; lane = channel.
// Walks NPART segments per conv (partitioned CSR).
// ---------------------------------------------------------------------------
__device__ __forceinline__ float gather_range(
    const float2* __restrict__ rec, const float* __restrict__ xm,
    int b, int e, int lane, float acc)
{
    int k = b;
    for (; k + 3 < e; k += 4) {
        const float2 r0 = rec[k];
        const float2 r1 = rec[k + 1];
        const float2 r2 = rec[k + 2];
        const float2 r3 = rec[k + 3];
        const float v0 = xm[__float_as_int(r0.x) * C + lane];
        const float v1 = xm[__float_as_int(r1.x) * C + lane];
        const float v2 = xm[__float_as_int(r2.x) * C + lane];
        const float v3 = xm[__float_as_int(r3.x) * C + lane];
        acc = fmaf(r0.y, v0, acc);
        acc = fmaf(r1.y, v1, acc);
        acc = fmaf(r2.y, v2, acc);
        acc = fmaf(r3.y, v3, acc);
    }
    for (; k < e; ++k) {
        const float2 r0 = rec[k];
        acc = fmaf(r0.y, xm[__float_as_int(r0.x) * C + lane], acc);
    }
    return acc;
}

__global__ __launch_bounds__(256) void gather_kernel(
    const float* __restrict__ xlin,
    const int* __restrict__ off, const float2* __restrict__ rec,
    const float* __restrict__ xm_l, const float* __restrict__ xm_u,
    float* __restrict__ out)
{
    const int node = blockIdx.x * 4 + (threadIdx.x >> 6);
    const int lane = threadIdx.x & 63;
    if (node >= N_NODES) return;

    float acc = xlin[node * C + lane];

#pragma unroll
    for (int p = 0; p < NPART; ++p) {
        const int f = p * TWO_N + node;
        acc = gather_range(rec, xm_l, off[f], off[f + 1], lane, acc);
    }
#pragma unroll
    for (int p = 0; p < NPART; ++p) {
        const int f = p * TWO_N + N_NODES + node;
        acc = gather_range(rec, xm_u, off[f], off[f + 1], lane, acc);
    }

    out[node * C + lane] = fmaxf(acc, 0.f);
}

extern "C" void kernel_launch(void* const* d_in, const int* in_sizes, int n_in,
                              void* d_out, int out_size, void* d_ws, size_t ws_size,
                              hipStream_t stream)
{
    const float* x          = (const float*)d_in[0];
    const int*   lower_idx  = (const int*)d_in[1];
    const float* lower_vals = (const float*)d_in[2];
    const int*   upper_idx  = (const int*)d_in[3];
    const float* upper_vals = (const float*)d_in[4];
    const float* w_lower    = (const float*)d_in[5];
    const float* a_lower    = (const float*)d_in[6];
    const float* w_upper    = (const float*)d_in[7];
    const float* a_upper    = (const float*)d_in[8];
    const float* w_lin      = (const float*)d_in[9];

    float* out = (float*)d_out;
    char* ws = (char*)d_ws;

    // ---- workspace layout ----
    const size_t NC = (size_t)N_NODES * C * sizeof(float);   // 12.8 MB
    float* xm_l = (float*)ws;                 ws += NC;
    float* xm_u = (float*)ws;                 ws += NC;
    float* xlin = (float*)ws;                 ws += NC;
    float* ssl  = (float*)ws;                 ws += N_NODES * sizeof(float);
    float* stl  = (float*)ws;                 ws += N_NODES * sizeof(float);
    float* ssu  = (float*)ws;                 ws += N_NODES * sizeof(float);
    float* stu  = (float*)ws;                 ws += N_NODES * sizeof(float);
    int* deg    = (int*)ws;                   ws += DEG_PAD * sizeof(int);       // padded
    int* off    = (int*)ws;                   ws += (DEG_SZ + 1) * sizeof(int);
    int* cur    = (int*)ws;                   ws += DEG_SZ * sizeof(int);
    int* bsum   = (int*)ws;                   ws += 1024 * sizeof(int);
    ws = (char*)(((size_t)ws + 15) & ~(size_t)15);
    float2* rec = (float2*)ws;                ws += (size_t)(2 * N_EDGES) * sizeof(float2); // 12.8 MB

    // zero the partitioned degree histogram (incl. scan padding)
    hipMemsetAsync(deg, 0, DEG_PAD * sizeof(int), stream);

    // A: per-node precompute (16 rows/block: 4 waves x 4 rows)
    precompute_kernel<<<(N_NODES + 15) / 16, 256, 0, stream>>>(
        x, w_lower, a_lower, w_upper, a_upper, w_lin,
        xm_l, xm_u, ssl, stl, ssu, stu, xlin);

    // B1: degree histogram (both convs, partitioned)
    hist_kernel<<<(2 * N_EDGES + 255) / 256, 256, 0, stream>>>(
        lower_idx, upper_idx, deg);

    // S1/S2/S3: multi-block exclusive scan -> off + cur
    block_sum_kernel<<<NB_SCAN, 256, 0, stream>>>(deg, bsum);
    scan_bsum_kernel<<<1, 1024, 0, stream>>>(bsum);
    scan_apply_kernel<<<NB_SCAN, 256, 0, stream>>>(deg, bsum, off, cur);

    // B3: CSR fill with per-edge alpha (partitioned rec)
    fill_kernel<<<(2 * N_EDGES + 255) / 256, 256, 0, stream>>>(
        lower_idx, lower_vals, ssl, stl,
        upper_idx, upper_vals, ssu, stu,
        cur, rec);

    // D: gather + skip + relu
    gather_kernel<<<(N_NODES + 3) / 4, 256, 0, stream>>>(
        xlin, off, rec, xm_l, xm_u, out);
}

// Round 5
// 423.809 us; speedup vs baseline: 1.0517x; 1.0517x over previous
//
#include <hip/hip_runtime.h>
#include <hip/hip_bf16.h>
#include <math.h>

#define N_NODES 50000
#define N_EDGES 800000
#define C 64
#define EPS_F 1.000001f
#define TWO_N (2 * N_NODES)

// CSR partitioned by edge-block cohort p = blockIdx & 7 (matches round-robin
// XCD dispatch) -> rec[] cache lines are written by one XCD (fixed the 8x HBM
// write amplification: 104 MB -> ~16 MB for a 12.8 MB array, round 3->4).
#define NPART 8
#define DEG_SZ (NPART * TWO_N)                          // 800000 bins
#define SCAN_TILE 1024
#define NB_SCAN ((DEG_SZ + SCAN_TILE - 1) / SCAN_TILE)  // 782 blocks
#define DEG_PAD (NB_SCAN * SCAN_TILE)
#define REC_MAX (2 * N_EDGES - 1)

// float -> bf16 bits, round-to-nearest-even
__device__ __forceinline__ unsigned short f2bf(float f) {
    unsigned u = __float_as_uint(f);
    return (unsigned short)((u + 0x7FFFu + ((u >> 16) & 1u)) >> 16);
}
__device__ __forceinline__ float bf2f(unsigned short b) {
    return __uint_as_float(((unsigned)b) << 16);
}

// ---------------------------------------------------------------------------
// Kernel A: per-node precompute. One wave per 4 node rows.
//   xm_* stored as bf16 (halves gather traffic); s_* and xlin in fp32.
// ---------------------------------------------------------------------------
__global__ __launch_bounds__(256) void precompute_kernel(
    const float* __restrict__ x,
    const float* __restrict__ w_l, const float* __restrict__ a_l,
    const float* __restrict__ w_u, const float* __restrict__ a_u,
    const float* __restrict__ w_lin,
    unsigned short* __restrict__ xm_l, unsigned short* __restrict__ xm_u,
    float* __restrict__ s_src_l, float* __restrict__ s_tgt_l,
    float* __restrict__ s_src_u, float* __restrict__ s_tgt_u,
    float* __restrict__ xlin)
{
    __shared__ float lw_l[C * C];
    __shared__ float lw_u[C * C];
    __shared__ float lw_n[C * C];
    __shared__ float la_l[2 * C];
    __shared__ float la_u[2 * C];

    const int t = threadIdx.x;
    for (int idx = t; idx < C * C; idx += 256) {
        lw_l[idx] = w_l[idx];
        lw_u[idx] = w_u[idx];
        lw_n[idx] = w_lin[idx];
    }
    if (t < 2 * C) { la_l[t] = a_l[t]; la_u[t] = a_u[t]; }
    __syncthreads();

    const int wave = t >> 6;
    const int lane = t & 63;
    const int row0 = (blockIdx.x * 4 + wave) * 4;

    float xv[4];
#pragma unroll
    for (int r = 0; r < 4; ++r) {
        const int row = row0 + r;
        xv[r] = (row < N_NODES) ? x[row * C + lane] : 0.f;
    }

    float acc_l[4] = {0.f, 0.f, 0.f, 0.f};
    float acc_u[4] = {0.f, 0.f, 0.f, 0.f};
    float acc_n[4] = {0.f, 0.f, 0.f, 0.f};

#pragma unroll 16
    for (int k = 0; k < C; ++k) {
        const float wl = lw_l[k * C + lane];
        const float wu = lw_u[k * C + lane];
        const float wn = lw_n[k * C + lane];
#pragma unroll
        for (int r = 0; r < 4; ++r) {
            const float xk = __shfl(xv[r], k);
            acc_l[r] = fmaf(xk, wl, acc_l[r]);
            acc_u[r] = fmaf(xk, wu, acc_u[r]);
            acc_n[r] = fmaf(xk, wn, acc_n[r]);
        }
    }

#pragma unroll
    for (int r = 0; r < 4; ++r) {
        const int row = row0 + r;
        if (row >= N_NODES) break;
        xm_l[row * C + lane] = f2bf(acc_l[r]);
        xm_u[row * C + lane] = f2bf(acc_u[r]);
        xlin[row * C + lane] = acc_n[r] * EPS_F;

        float ssl = acc_l[r] * la_l[lane];
        float stl = acc_l[r] * la_l[C + lane];
        float ssu = acc_u[r] * la_u[lane];
        float stu = acc_u[r] * la_u[C + lane];
#pragma unroll
        for (int off = 32; off >= 1; off >>= 1) {
            ssl += __shfl_xor(ssl, off);
            stl += __shfl_xor(stl, off);
            ssu += __shfl_xor(ssu, off);
            stu += __shfl_xor(stu, off);
        }
        if (lane == 0) {
            s_src_l[row] = ssl;
            s_tgt_l[row] = stl;
            s_src_u[row] = ssu;
            s_tgt_u[row] = stu;
        }
    }
}

// ---------------------------------------------------------------------------
// Kernel B1: degree histogram into partitioned bins deg[p][cv][node].
// ---------------------------------------------------------------------------
__global__ __launch_bounds__(256) void hist_kernel(
    const int* __restrict__ lidx, const int* __restrict__ uidx,
    int* __restrict__ deg)
{
    const int g = blockIdx.x * 256 + threadIdx.x;
    const int p = blockIdx.x & (NPART - 1);
    if (g >= 2 * N_EDGES) return;
    if (g < N_EDGES) atomicAdd(&deg[p * TWO_N + lidx[g]], 1);
    else             atomicAdd(&deg[p * TWO_N + N_NODES + uidx[g - N_EDGES]], 1);
}

// ---------------------------------------------------------------------------
// Kernel S1: per-tile sums (1024 elems / block, int4 loads). deg zero-padded.
// ---------------------------------------------------------------------------
__global__ __launch_bounds__(256) void block_sum_kernel(
    const int* __restrict__ deg, int* __restrict__ bsum)
{
    const int t = threadIdx.x;
    const int4 d = ((const int4*)deg)[blockIdx.x * 256 + t];
    int v = d.x + d.y + d.z + d.w;
#pragma unroll
    for (int o = 32; o >= 1; o >>= 1) v += __shfl_xor(v, o);
    __shared__ int ws[4];
    if ((t & 63) == 0) ws[t >> 6] = v;
    __syncthreads();
    if (t == 0) bsum[blockIdx.x] = ws[0] + ws[1] + ws[2] + ws[3];
}

// ---------------------------------------------------------------------------
// Kernel S2: inclusive scan of NB_SCAN (<=1024) tile sums.
// ---------------------------------------------------------------------------
__global__ __launch_bounds__(1024) void scan_bsum_kernel(int* __restrict__ bsum)
{
    __shared__ int s[1024];
    const int t = threadIdx.x;
    s[t] = (t < NB_SCAN) ? bsum[t] : 0;
    __syncthreads();
    for (int o = 1; o < 1024; o <<= 1) {
        const int y = (t >= o) ? s[t - o] : 0;
        __syncthreads();
        s[t] += y;
        __syncthreads();
    }
    if (t < NB_SCAN) bsum[t] = s[t];
}

// ---------------------------------------------------------------------------
// Kernel S3: apply — exclusive scan of deg into off[] / cur[].
// ---------------------------------------------------------------------------
__global__ __launch_bounds__(256) void scan_apply_kernel(
    const int* __restrict__ deg, const int* __restrict__ bscan,
    int* __restrict__ off, int* __restrict__ cur)
{
    const int b = blockIdx.x, t = threadIdx.x;
    const int lane = t & 63, wv = t >> 6;
    const int g4 = (b * 256 + t) * 4;

    const int4 d = ((const int4*)deg)[b * 256 + t];
    int e0 = 0, e1 = d.x, e2 = d.x + d.y, e3 = d.x + d.y + d.z;
    const int tot = e3 + d.w;

    int inc = tot;
#pragma unroll
    for (int o = 1; o < 64; o <<= 1) {
        const int y = __shfl_up(inc, o);
        if (lane >= o) inc += y;
    }
    __shared__ int wsum[4];
    if (lane == 63) wsum[wv] = inc;
    __syncthreads();
    int wpre = 0;
    for (int w = 0; w < wv; ++w) wpre += wsum[w];

    const int bpre = (b == 0) ? 0 : bscan[b - 1];
    const int base = bpre + wpre + (inc - tot);

    const int vals[4] = { base + e0, base + e1, base + e2, base + e3 };
#pragma unroll
    for (int k = 0; k < 4; ++k) {
        const int f = g4 + k;
        if (f < DEG_SZ) { off[f] = vals[k]; cur[f] = vals[k]; }
        else if (f == DEG_SZ) { off[f] = vals[k]; }
    }
}

// ---------------------------------------------------------------------------
// Kernel B3: CSR fill into partitioned rec[].
// ---------------------------------------------------------------------------
__global__ __launch_bounds__(256) void fill_kernel(
    const int* __restrict__ lidx, const float* __restrict__ lval,
    const float* __restrict__ ssl, const float* __restrict__ stl,
    const int* __restrict__ uidx, const float* __restrict__ uval,
    const float* __restrict__ ssu, const float* __restrict__ stu,
    int* __restrict__ cur, float2* __restrict__ rec)
{
    const int g = blockIdx.x * 256 + threadIdx.x;
    const int p = blockIdx.x & (NPART - 1);
    if (g >= 2 * N_EDGES) return;

    if (g < N_EDGES) {
        const int e = g;
        const int i = lidx[e];
        const int j = lidx[N_EDGES + e];
        float s = ssl[j] + stl[i];
        s = (s > 0.f) ? s : expm1f(s);
        const float a = s * lval[e];
        const int slot = atomicAdd(&cur[p * TWO_N + i], 1);
        rec[slot] = make_float2(__int_as_float(j), a);
    } else {
        const int e = g - N_EDGES;
        const int i = uidx[e];
        const int j = uidx[N_EDGES + e];
        float s = ssu[j] + stu[i];
        s = (s > 0.f) ? s : expm1f(s);
        const float a = s * uval[e];
        const int slot = atomicAdd(&cur[p * TWO_N + N_NODES + i], 1);
        rec[slot] = make_float2(__int_as_float(j), a);
    }
}

// ---------------------------------------------------------------------------
// Kernel D: gather + fuse. One BLOCK (4 waves) per node; lane = channel.
// Wave w owns conv = w>>1, partitions (w&1)*4 .. +3, walked with 4
// independent branchless cursors (4 rec + 4 row loads in flight).
// LDS reduce across waves, + xlin, ReLU, single coalesced store.
// ---------------------------------------------------------------------------
__global__ __launch_bounds__(256) void gather_kernel(
    const float* __restrict__ xlin,
    const int* __restrict__ off, const float2* __restrict__ rec,
    const unsigned short* __restrict__ xm_l, const unsigned short* __restrict__ xm_u,
    float* __restrict__ out)
{
    const int node = blockIdx.x;
    const int wv = threadIdx.x >> 6;
    const int lane = threadIdx.x & 63;
    const int conv = wv >> 1;
    const unsigned short* __restrict__ xm = conv ? xm_u : xm_l;
    const int pbase = (wv & 1) * 4;

    // prefetch the skip branch early (wave 0 only)
    float xl = 0.f;
    if (wv == 0) xl = xlin[node * C + lane];

    int ks[4], es[4];
#pragma unroll
    for (int s = 0; s < 4; ++s) {
        const int f = (pbase + s) * TWO_N + conv * N_NODES + node;
        ks[s] = off[f];
        es[s] = off[f + 1];
    }

    float acc = 0.f;
    while ((ks[0] < es[0]) | (ks[1] < es[1]) | (ks[2] < es[2]) | (ks[3] < es[3])) {
        bool a[4];
        float2 r[4];
#pragma unroll
        for (int s = 0; s < 4; ++s) {
            a[s] = ks[s] < es[s];
            r[s] = rec[min(ks[s], REC_MAX)];
        }
        float v[4];
#pragma unroll
        for (int s = 0; s < 4; ++s) {
            const int j = a[s] ? __float_as_int(r[s].x) : 0;
            v[s] = bf2f(xm[j * C + lane]);
        }
#pragma unroll
        for (int s = 0; s < 4; ++s) {
            const float w = a[s] ? r[s].y : 0.f;
            acc = fmaf(w, v[s], acc);
            ks[s] += a[s] ? 1 : 0;
        }
    }

    __shared__ float red[4 * C];
    red[wv * C + lane] = acc;
    __syncthreads();
    if (wv == 0) {
        float sum = xl + red[lane] + red[C + lane] + red[2 * C + lane] + red[3 * C + lane];
        out[node * C + lane] = fmaxf(sum, 0.f);
    }
}

extern "C" void kernel_launch(void* const* d_in, const int* in_sizes, int n_in,
                              void* d_out, int out_size, void* d_ws, size_t ws_size,
                              hipStream_t stream)
{
    const float* x          = (const float*)d_in[0];
    const int*   lower_idx  = (const int*)d_in[1];
    const float* lower_vals = (const float*)d_in[2];
    const int*   upper_idx  = (const int*)d_in[3];
    const float* upper_vals = (const float*)d_in[4];
    const float* w_lower    = (const float*)d_in[5];
    const float* a_lower    = (const float*)d_in[6];
    const float* w_upper    = (const float*)d_in[7];
    const float* a_upper    = (const float*)d_in[8];
    const float* w_lin      = (const float*)d_in[9];

    float* out = (float*)d_out;
    char* ws = (char*)d_ws;

    // ---- workspace layout ----
    const size_t NC_F = (size_t)N_NODES * C * sizeof(float);          // 12.8 MB
    const size_t NC_H = (size_t)N_NODES * C * sizeof(unsigned short); // 6.4 MB
    unsigned short* xm_l = (unsigned short*)ws;  ws += NC_H;
    unsigned short* xm_u = (unsigned short*)ws;  ws += NC_H;
    float* xlin = (float*)ws;                 ws += NC_F;
    float* ssl  = (float*)ws;                 ws += N_NODES * sizeof(float);
    float* stl  = (float*)ws;                 ws += N_NODES * sizeof(float);
    float* ssu  = (float*)ws;                 ws += N_NODES * sizeof(float);
    float* stu  = (float*)ws;                 ws += N_NODES * sizeof(float);
    int* deg    = (int*)ws;                   ws += DEG_PAD * sizeof(int);
    int* off    = (int*)ws;                   ws += (DEG_SZ + 1) * sizeof(int);
    int* cur    = (int*)ws;                   ws += DEG_SZ * sizeof(int);
    int* bsum   = (int*)ws;                   ws += 1024 * sizeof(int);
    ws = (char*)(((size_t)ws + 15) & ~(size_t)15);
    float2* rec = (float2*)ws;                ws += (size_t)(2 * N_EDGES) * sizeof(float2);

    hipMemsetAsync(deg, 0, DEG_PAD * sizeof(int), stream);

    precompute_kernel<<<(N_NODES + 15) / 16, 256, 0, stream>>>(
        x, w_lower, a_lower, w_upper, a_upper, w_lin,
        xm_l, xm_u, ssl, stl, ssu, stu, xlin);

    hist_kernel<<<(2 * N_EDGES + 255) / 256, 256, 0, stream>>>(
        lower_idx, upper_idx, deg);

    block_sum_kernel<<<NB_SCAN, 256, 0, stream>>>(deg, bsum);
    scan_bsum_kernel<<<1, 1024, 0, stream>>>(bsum);
    scan_apply_kernel<<<NB_SCAN, 256, 0, stream>>>(deg, bsum, off, cur);

    fill_kernel<<<(2 * N_EDGES + 255) / 256, 256, 0, stream>>>(
        lower_idx, lower_vals, ssl, stl,
        upper_idx, upper_vals, ssu, stu,
        cur, rec);

    gather_kernel<<<N_NODES, 256, 0, stream>>>(
        xlin, off, rec, xm_l, xm_u, out);
}

// Round 6
// 351.366 us; speedup vs baseline: 1.2686x; 1.2062x over previous
//
#include <hip/hip_runtime.h>
#include <hip/hip_bf16.h>
#include <math.h>

#define N_NODES 50000
#define N_EDGES 800000
#define C 64
#define EPS_F 1.000001f
#define TWO_N (2 * N_NODES)

// CSR partitioned by edge-block cohort p = blockIdx & 3. Round-robin XCD
// dispatch puts cohort p on XCDs {p, p+4} -> rec[] cache lines written by a
// fixed 2-XCD set (round 3's unpartitioned fill had 8x HBM write amp; NPART=8
// fixed it but fragmented gather segments to avg len 2; NPART=4 is the
// compromise: avg seg len 4 = one 4-record chunk, ~2x write amp in fill).
#define NPART 4
#define DEG_SZ (NPART * TWO_N)                          // 400000 bins
#define SCAN_TILE 1024
#define NB_SCAN ((DEG_SZ + SCAN_TILE - 1) / SCAN_TILE)  // 391 blocks
#define DEG_PAD (NB_SCAN * SCAN_TILE)                   // 400384

// float -> bf16 bits, round-to-nearest-even
__device__ __forceinline__ unsigned short f2bf(float f) {
    unsigned u = __float_as_uint(f);
    return (unsigned short)((u + 0x7FFFu + ((u >> 16) & 1u)) >> 16);
}
__device__ __forceinline__ float bf2f(unsigned short b) {
    return __uint_as_float(((unsigned)b) << 16);
}

// ---------------------------------------------------------------------------
// Kernel A: per-node precompute (one wave per 4 rows) + zero deg[] (fused so
// no separate memset dispatch; hist runs after us in stream order).
// ---------------------------------------------------------------------------
__global__ __launch_bounds__(256) void precompute_kernel(
    const float* __restrict__ x,
    const float* __restrict__ w_l, const float* __restrict__ a_l,
    const float* __restrict__ w_u, const float* __restrict__ a_u,
    const float* __restrict__ w_lin,
    unsigned short* __restrict__ xm_l, unsigned short* __restrict__ xm_u,
    float* __restrict__ s_src_l, float* __restrict__ s_tgt_l,
    float* __restrict__ s_src_u, float* __restrict__ s_tgt_u,
    float* __restrict__ xlin, int* __restrict__ deg)
{
    __shared__ float lw_l[C * C];
    __shared__ float lw_u[C * C];
    __shared__ float lw_n[C * C];
    __shared__ float la_l[2 * C];
    __shared__ float la_u[2 * C];

    const int t = threadIdx.x;

    // fused deg zeroing: grid is 3125*256 = 800000 threads >= DEG_PAD
    const int gz = blockIdx.x * 256 + t;
    if (gz < DEG_PAD) deg[gz] = 0;

    for (int idx = t; idx < C * C; idx += 256) {
        lw_l[idx] = w_l[idx];
        lw_u[idx] = w_u[idx];
        lw_n[idx] = w_lin[idx];
    }
    if (t < 2 * C) { la_l[t] = a_l[t]; la_u[t] = a_u[t]; }
    __syncthreads();

    const int wave = t >> 6;
    const int lane = t & 63;
    const int row0 = (blockIdx.x * 4 + wave) * 4;

    float xv[4];
#pragma unroll
    for (int r = 0; r < 4; ++r) {
        const int row = row0 + r;
        xv[r] = (row < N_NODES) ? x[row * C + lane] : 0.f;
    }

    float acc_l[4] = {0.f, 0.f, 0.f, 0.f};
    float acc_u[4] = {0.f, 0.f, 0.f, 0.f};
    float acc_n[4] = {0.f, 0.f, 0.f, 0.f};

#pragma unroll 16
    for (int k = 0; k < C; ++k) {
        const float wl = lw_l[k * C + lane];
        const float wu = lw_u[k * C + lane];
        const float wn = lw_n[k * C + lane];
#pragma unroll
        for (int r = 0; r < 4; ++r) {
            const float xk = __shfl(xv[r], k);
            acc_l[r] = fmaf(xk, wl, acc_l[r]);
            acc_u[r] = fmaf(xk, wu, acc_u[r]);
            acc_n[r] = fmaf(xk, wn, acc_n[r]);
        }
    }

#pragma unroll
    for (int r = 0; r < 4; ++r) {
        const int row = row0 + r;
        if (row >= N_NODES) break;
        xm_l[row * C + lane] = f2bf(acc_l[r]);
        xm_u[row * C + lane] = f2bf(acc_u[r]);
        xlin[row * C + lane] = acc_n[r] * EPS_F;

        float ssl = acc_l[r] * la_l[lane];
        float stl = acc_l[r] * la_l[C + lane];
        float ssu = acc_u[r] * la_u[lane];
        float stu = acc_u[r] * la_u[C + lane];
#pragma unroll
        for (int off = 32; off >= 1; off >>= 1) {
            ssl += __shfl_xor(ssl, off);
            stl += __shfl_xor(stl, off);
            ssu += __shfl_xor(ssu, off);
            stu += __shfl_xor(stu, off);
        }
        if (lane == 0) {
            s_src_l[row] = ssl;
            s_tgt_l[row] = stl;
            s_src_u[row] = ssu;
            s_tgt_u[row] = stu;
        }
    }
}

// ---------------------------------------------------------------------------
// Kernel B1: degree histogram + per-edge rank (atomicAdd return value).
// rank makes fill atomic-free. Partition p = blockIdx & 3 (must match fill's
// grid mapping — both use g = blockIdx*256 + tid over 2E threads).
// ---------------------------------------------------------------------------
__global__ __launch_bounds__(256) void hist_kernel(
    const int* __restrict__ lidx, const int* __restrict__ uidx,
    int* __restrict__ deg, int* __restrict__ rank)
{
    const int g = blockIdx.x * 256 + threadIdx.x;
    const int p = blockIdx.x & (NPART - 1);
    if (g >= 2 * N_EDGES) return;
    int bin;
    if (g < N_EDGES) bin = p * TWO_N + lidx[g];
    else             bin = p * TWO_N + N_NODES + uidx[g - N_EDGES];
    rank[g] = atomicAdd(&deg[bin], 1);
}

// ---------------------------------------------------------------------------
// Kernel S1: per-tile sums (1024 elems / block, int4 loads). deg zero-padded.
// ---------------------------------------------------------------------------
__global__ __launch_bounds__(256) void block_sum_kernel(
    const int* __restrict__ deg, int* __restrict__ bsum)
{
    const int t = threadIdx.x;
    const int4 d = ((const int4*)deg)[blockIdx.x * 256 + t];
    int v = d.x + d.y + d.z + d.w;
#pragma unroll
    for (int o = 32; o >= 1; o >>= 1) v += __shfl_xor(v, o);
    __shared__ int ws[4];
    if ((t & 63) == 0) ws[t >> 6] = v;
    __syncthreads();
    if (t == 0) bsum[blockIdx.x] = ws[0] + ws[1] + ws[2] + ws[3];
}

// ---------------------------------------------------------------------------
// Kernel S2: apply — exclusive scan of deg into off[]. Each block computes its
// own prefix over the 391 tile sums (redundant but tiny: 2 masked loads/thread)
// — eliminates the separate middle scan dispatch.
// ---------------------------------------------------------------------------
__global__ __launch_bounds__(256) void scan_apply_kernel(
    const int* __restrict__ deg, const int* __restrict__ bsum,
    int* __restrict__ off)
{
    const int b = blockIdx.x, t = threadIdx.x;
    const int lane = t & 63, wv = t >> 6;

    // bpre = sum of bsum[0..b)
    int part = 0;
    for (int i = t; i < NB_SCAN; i += 256)
        part += (i < b) ? bsum[i] : 0;
#pragma unroll
    for (int o = 32; o >= 1; o >>= 1) part += __shfl_xor(part, o);
    __shared__ int pre4[4];
    if (lane == 0) pre4[wv] = part;
    __syncthreads();
    const int bpre = pre4[0] + pre4[1] + pre4[2] + pre4[3];

    const int g4 = (b * 256 + t) * 4;
    const int4 d = ((const int4*)deg)[b * 256 + t];
    const int e1 = d.x, e2 = d.x + d.y, e3 = d.x + d.y + d.z;
    const int tot = e3 + d.w;

    int inc = tot;
#pragma unroll
    for (int o = 1; o < 64; o <<= 1) {
        const int y = __shfl_up(inc, o);
        if (lane >= o) inc += y;
    }
    __shared__ int wsum[4];
    if (lane == 63) wsum[wv] = inc;
    __syncthreads();
    int wpre = 0;
    for (int w = 0; w < wv; ++w) wpre += wsum[w];

    const int base = bpre + wpre + (inc - tot);
    const int vals[4] = { base, base + e1, base + e2, base + e3 };
#pragma unroll
    for (int k = 0; k < 4; ++k) {
        const int f = g4 + k;
        if (f < DEG_SZ) off[f] = vals[k];
        else if (f == DEG_SZ) off[f] = vals[k];
    }
}

// ---------------------------------------------------------------------------
// Kernel B3: CSR fill, atomic-free: slot = off[bin] + rank[g].
// ---------------------------------------------------------------------------
__global__ __launch_bounds__(256) void fill_kernel(
    const int* __restrict__ lidx, const float* __restrict__ lval,
    const float* __restrict__ ssl, const float* __restrict__ stl,
    const int* __restrict__ uidx, const float* __restrict__ uval,
    const float* __restrict__ ssu, const float* __restrict__ stu,
    const int* __restrict__ off, const int* __restrict__ rank,
    float2* __restrict__ rec)
{
    const int g = blockIdx.x * 256 + threadIdx.x;
    const int p = blockIdx.x & (NPART - 1);
    if (g >= 2 * N_EDGES) return;

    int bin, j;
    float s, v;
    if (g < N_EDGES) {
        const int e = g;
        const int i = lidx[e];
        j = lidx[N_EDGES + e];
        v = lval[e];
        s = ssl[j] + stl[i];
        bin = p * TWO_N + i;
    } else {
        const int e = g - N_EDGES;
        const int i = uidx[e];
        j = uidx[N_EDGES + e];
        v = uval[e];
        s = ssu[j] + stu[i];
        bin = p * TWO_N + N_NODES + i;
    }
    s = (s > 0.f) ? s : expm1f(s);
    const float a = s * v;
    const int slot = off[bin] + rank[g];
    rec[slot] = make_float2(__int_as_float(j), a);
}

// ---------------------------------------------------------------------------
// Kernel D: gather + fuse. One BLOCK per node. Wave w: conv = w>>1,
// partitions (w&1)*2 .. +1. Within a wave: sub = lane>>4 picks one of 4
// sequential records per chunk, cg = lane&15 picks 4 channels (ushort4 load).
// One wave-wide row-load instruction serves 4 records -> 4x fewer VMEM
// instructions and ~2x less VALU per record than the round-5 cursor design.
// ---------------------------------------------------------------------------
__global__ __launch_bounds__(256) void gather_kernel(
    const float* __restrict__ xlin,
    const int* __restrict__ off, const float2* __restrict__ rec,
    const unsigned short* __restrict__ xm_l, const unsigned short* __restrict__ xm_u,
    float* __restrict__ out)
{
    const int node = blockIdx.x;
    const int wv = threadIdx.x >> 6;
    const int lane = threadIdx.x & 63;
    const int conv = wv >> 1;
    const int pbase = (wv & 1) * 2;
    const unsigned short* __restrict__ xm = conv ? xm_u : xm_l;
    const int sub = lane >> 4;     // record slot within 4-chunk
    const int cg = lane & 15;      // channel group: channels cg*4 .. +3

    float4 acc = make_float4(0.f, 0.f, 0.f, 0.f);

#pragma unroll
    for (int sseg = 0; sseg < 2; ++sseg) {
        const int f = (pbase + sseg) * TWO_N + conv * N_NODES + node;
        int k = off[f];
        const int e = off[f + 1];
        while (k < e) {
            const int idx = k + sub;
            const bool act = idx < e;
            const float2 r = rec[act ? idx : k];
            const int j = act ? __float_as_int(r.x) : 0;
            const float w = act ? r.y : 0.f;
            const ushort4 row = *(const ushort4*)(xm + j * C + cg * 4);
            acc.x = fmaf(w, bf2f(row.x), acc.x);
            acc.y = fmaf(w, bf2f(row.y), acc.y);
            acc.z = fmaf(w, bf2f(row.z), acc.z);
            acc.w = fmaf(w, bf2f(row.w), acc.w);
            k += 4;
        }
    }

    // reduce across the 4 record-slots (lane>>4) within the wave
    acc.x += __shfl_xor(acc.x, 16);
    acc.y += __shfl_xor(acc.y, 16);
    acc.z += __shfl_xor(acc.z, 16);
    acc.w += __shfl_xor(acc.w, 16);
    acc.x += __shfl_xor(acc.x, 32);
    acc.y += __shfl_xor(acc.y, 32);
    acc.z += __shfl_xor(acc.z, 32);
    acc.w += __shfl_xor(acc.w, 32);

    __shared__ float4 red[4][16];
    if (lane < 16) red[wv][lane] = acc;
    __syncthreads();
    if (wv == 0 && lane < 16) {
        const float4 a0 = red[0][lane];
        const float4 a1 = red[1][lane];
        const float4 a2 = red[2][lane];
        const float4 a3 = red[3][lane];
        const float4 xl = *(const float4*)(xlin + node * C + lane * 4);
        float4 o;
        o.x = fmaxf(xl.x + a0.x + a1.x + a2.x + a3.x, 0.f);
        o.y = fmaxf(xl.y + a0.y + a1.y + a2.y + a3.y, 0.f);
        o.z = fmaxf(xl.z + a0.z + a1.z + a2.z + a3.z, 0.f);
        o.w = fmaxf(xl.w + a0.w + a1.w + a2.w + a3.w, 0.f);
        *(float4*)(out + node * C + lane * 4) = o;
    }
}

extern "C" void kernel_launch(void* const* d_in, const int* in_sizes, int n_in,
                              void* d_out, int out_size, void* d_ws, size_t ws_size,
                              hipStream_t stream)
{
    const float* x          = (const float*)d_in[0];
    const int*   lower_idx  = (const int*)d_in[1];
    const float* lower_vals = (const float*)d_in[2];
    const int*   upper_idx  = (const int*)d_in[3];
    const float* upper_vals = (const float*)d_in[4];
    const float* w_lower    = (const float*)d_in[5];
    const float* a_lower    = (const float*)d_in[6];
    const float* w_upper    = (const float*)d_in[7];
    const float* a_upper    = (const float*)d_in[8];
    const float* w_lin      = (const float*)d_in[9];

    float* out = (float*)d_out;
    char* ws = (char*)d_ws;

    // ---- workspace layout (all chunks 16B-multiple sized) ----
    const size_t NC_F = (size_t)N_NODES * C * sizeof(float);          // 12.8 MB
    const size_t NC_H = (size_t)N_NODES * C * sizeof(unsigned short); // 6.4 MB
    unsigned short* xm_l = (unsigned short*)ws;  ws += NC_H;
    unsigned short* xm_u = (unsigned short*)ws;  ws += NC_H;
    float* xlin = (float*)ws;                 ws += NC_F;
    float* ssl  = (float*)ws;                 ws += N_NODES * sizeof(float);
    float* stl  = (float*)ws;                 ws += N_NODES * sizeof(float);
    float* ssu  = (float*)ws;                 ws += N_NODES * sizeof(float);
    float* stu  = (float*)ws;                 ws += N_NODES * sizeof(float);
    int* deg    = (int*)ws;                   ws += DEG_PAD * sizeof(int);
    int* off    = (int*)ws;                   ws += (DEG_SZ + 16) * sizeof(int);
    int* rank   = (int*)ws;                   ws += (size_t)(2 * N_EDGES) * sizeof(int); // 6.4 MB
    int* bsum   = (int*)ws;                   ws += ((NB_SCAN + 15) & ~15) * sizeof(int);
    float2* rec = (float2*)ws;                ws += (size_t)(2 * N_EDGES) * sizeof(float2); // 12.8 MB

    // A: precompute + fused deg zeroing (3125 blocks * 256 thr >= DEG_PAD)
    precompute_kernel<<<(N_NODES + 15) / 16, 256, 0, stream>>>(
        x, w_lower, a_lower, w_upper, a_upper, w_lin,
        xm_l, xm_u, ssl, stl, ssu, stu, xlin, deg);

    // B1: histogram + rank
    hist_kernel<<<(2 * N_EDGES + 255) / 256, 256, 0, stream>>>(
        lower_idx, upper_idx, deg, rank);

    // S1/S2: scan -> off
    block_sum_kernel<<<NB_SCAN, 256, 0, stream>>>(deg, bsum);
    scan_apply_kernel<<<NB_SCAN, 256, 0, stream>>>(deg, bsum, off);

    // B3: atomic-free CSR fill
    fill_kernel<<<(2 * N_EDGES + 255) / 256, 256, 0, stream>>>(
        lower_idx, lower_vals, ssl, stl,
        upper_idx, upper_vals, ssu, stu,
        off, rank, rec);

    // D: gather + skip + relu
    gather_kernel<<<N_NODES, 256, 0, stream>>>(
        xlin, off, rec, xm_l, xm_u, out);
}